// Round 1
// baseline (476.977 us; speedup 1.0000x reference)
//
#include <hip/hip_runtime.h>

typedef unsigned short u16;
typedef __attribute__((ext_vector_type(8))) short short8;   // 8 bf16 (4 VGPRs) MFMA frag
typedef __attribute__((ext_vector_type(4))) float f32x4;
typedef __attribute__((ext_vector_type(4))) unsigned short u16x4;
typedef __attribute__((ext_vector_type(8))) unsigned short u16x8;

#define BTOK 16384      // B*S = 4*4096
#define PROJ_N 2576
#define PROJ_PAD 2688   // 21 * 128
#define DK 1024         // D_MODEL = D_INNER
#define NCH 256         // B * nChunks = 4*64
#define NH 16
#define HD 64
#define NS 16           // D_STATE

__device__ __forceinline__ float b2f(u16 b) {
    union { unsigned int u; float f; } v; v.u = ((unsigned int)b) << 16; return v.f;
}
__device__ __forceinline__ u16 f2b(float f) {
    union { float f; unsigned int u; } v; v.f = f;
    unsigned int r = v.u + 0x7fffu + ((v.u >> 16) & 1u);
    return (u16)(r >> 16);
}

// ---------------- casts ----------------
__global__ __launch_bounds__(256) void cast_bf16(const float* __restrict__ s,
                                                 u16* __restrict__ d, int n4) {
    int t = blockIdx.x * 256 + threadIdx.x;
    if (t < n4) {
        float4 v = ((const float4*)s)[t];
        u16x4 o; o.x = f2b(v.x); o.y = f2b(v.y); o.z = f2b(v.z); o.w = f2b(v.w);
        ((u16x4*)d)[t] = o;
    }
}

// W_in (2576x1024) -> bf16 padded to (2688x1024), pad rows zero
__global__ __launch_bounds__(256) void cast_pad_win(const float* __restrict__ s,
                                                    u16* __restrict__ d) {
    int t = blockIdx.x * 256 + threadIdx.x;   // 0 .. 2688*1024/4-1
    int i4 = t * 4;
    float4 v = make_float4(0.f, 0.f, 0.f, 0.f);
    if (i4 < PROJ_N * DK) v = ((const float4*)s)[t];
    u16x4 o; o.x = f2b(v.x); o.y = f2b(v.y); o.z = f2b(v.z); o.w = f2b(v.w);
    ((u16x4*)d)[t] = o;
}

// ---------------- GEMM: C[M,N] = A[M,K] * B[N,K]^T, bf16 in, fp32 acc ----------------
template <int OUT_BF16>
__global__ __launch_bounds__(256) void gemm_bt(const u16* __restrict__ A,
                                               const u16* __restrict__ B,
                                               float* __restrict__ Cf,
                                               u16* __restrict__ Cb,
                                               int K, int ldc) {
    __shared__ u16 As[128][72];
    __shared__ u16 Bs[128][72];
    const int tid = threadIdx.x;
    const int bm = blockIdx.x, bn = blockIdx.y;
    const int wave = tid >> 6, lane = tid & 63;
    const int wm = (wave >> 1) * 64, wn = (wave & 1) * 64;
    const int m_l = lane & 15, quad = lane >> 4;

    f32x4 acc[4][4];
#pragma unroll
    for (int i = 0; i < 4; ++i)
#pragma unroll
        for (int j = 0; j < 4; ++j) acc[i][j] = (f32x4){0.f, 0.f, 0.f, 0.f};

    const long arow0 = (long)bm * 128;
    const long brow0 = (long)bn * 128;

    for (int k0 = 0; k0 < K; k0 += 64) {
#pragma unroll
        for (int it = 0; it < 4; ++it) {
            int li = it * 256 + tid;          // 0..1023
            int r = li >> 3, c8 = (li & 7) * 8;
            u16x8 av = *(const u16x8*)(A + (arow0 + r) * K + k0 + c8);
            *(u16x8*)(&As[r][c8]) = av;
            u16x8 bv = *(const u16x8*)(B + (brow0 + r) * K + k0 + c8);
            *(u16x8*)(&Bs[r][c8]) = bv;
        }
        __syncthreads();
#pragma unroll
        for (int ks = 0; ks < 2; ++ks) {
            const int kc = ks * 32 + quad * 8;
            short8 af[4], bf[4];
#pragma unroll
            for (int i = 0; i < 4; ++i) af[i] = *(const short8*)(&As[wm + i * 16 + m_l][kc]);
#pragma unroll
            for (int j = 0; j < 4; ++j) bf[j] = *(const short8*)(&Bs[wn + j * 16 + m_l][kc]);
#pragma unroll
            for (int i = 0; i < 4; ++i)
#pragma unroll
                for (int j = 0; j < 4; ++j)
                    acc[i][j] = __builtin_amdgcn_mfma_f32_16x16x32_bf16(af[i], bf[j], acc[i][j], 0, 0, 0);
        }
        __syncthreads();
    }
    // epilogue: C/D layout col=lane&15, row=quad*4+reg
#pragma unroll
    for (int i = 0; i < 4; ++i) {
        int row_base = bm * 128 + wm + i * 16 + quad * 4;
#pragma unroll
        for (int j = 0; j < 4; ++j) {
            int col = bn * 128 + wn + j * 16 + m_l;
#pragma unroll
            for (int r = 0; r < 4; ++r) {
                float v = acc[i][j][r];
                long off = (long)(row_base + r) * ldc + col;
                if (OUT_BF16) Cb[off] = f2b(v);
                else          Cf[off] = v;
            }
        }
    }
}

// ---------------- dt: softplus(dt_low @ dt_W^T + dt_b), dA cumsum per chunk ----------------
__global__ __launch_bounds__(64) void compute_dt(const u16* __restrict__ proj,
                                                 const float* __restrict__ dt_W,
                                                 const float* __restrict__ dt_b,
                                                 const float* __restrict__ A_log,
                                                 float* __restrict__ dt,
                                                 float* __restrict__ dAcs,
                                                 float* __restrict__ decay) {
    int bc = blockIdx.x;          // 0..255 = b*64+c
    int i = threadIdx.x;          // token within chunk
    long tok = (long)bc * 64 + i;
    float low[16];
#pragma unroll
    for (int r = 0; r < 16; ++r) low[r] = b2f(proj[tok * PROJ_PAD + 2560 + r]);
#pragma unroll
    for (int h = 0; h < 16; ++h) {
        float a = dt_b[h];
#pragma unroll
        for (int r = 0; r < 16; ++r) a += low[r] * dt_W[h * 16 + r];
        float d = (a > 20.f) ? a : log1pf(__expf(a));
        float dA = -__expf(A_log[h]) * d;
        float cs = dA;
#pragma unroll
        for (int off = 1; off < 64; off <<= 1) {
            float o = __shfl_up(cs, off, 64);
            if (i >= off) cs += o;
        }
        dt[tok * 16 + h] = d;
        dAcs[tok * 16 + h] = cs;
        if (i == 63) decay[bc * 16 + h] = __expf(cs);
    }
}

// ---------------- intra-chunk: scores, y_intra, chunk_state ----------------
__global__ __launch_bounds__(256) void ssm_intra(const u16* __restrict__ proj,
                                                 const float* __restrict__ dt,
                                                 const float* __restrict__ dAcs,
                                                 u16* __restrict__ y_acc,
                                                 float* __restrict__ cstate) {
    int bch = blockIdx.x;             // 4096 = (b*64+c)*16 + h
    int bc = bch >> 4, h = bch & 15;
    long tok0 = (long)bc * 64;
    __shared__ float Cs[64][16], Bm[64][16], xs[64][64], sc[64][64];
    __shared__ float dts[64], dAs[64], wk[64];
    int tid = threadIdx.x;
#pragma unroll
    for (int it = 0; it < 4; ++it) {
        int li = it * 256 + tid;
        int i = li >> 4, n = li & 15;
        Cs[i][n] = b2f(proj[(tok0 + i) * PROJ_PAD + 2304 + h * 16 + n]);
        Bm[i][n] = b2f(proj[(tok0 + i) * PROJ_PAD + 2048 + h * 16 + n]);
    }
#pragma unroll
    for (int it = 0; it < 16; ++it) {
        int li = it * 256 + tid;
        int i = li >> 6, p = li & 63;
        xs[i][p] = b2f(proj[(tok0 + i) * PROJ_PAD + h * 64 + p]);
    }
    if (tid < 64) {
        dts[tid] = dt[(tok0 + tid) * 16 + h];
        dAs[tid] = dAcs[(tok0 + tid) * 16 + h];
    }
    __syncthreads();
    if (tid < 64) wk[tid] = dts[tid] * __expf(dAs[63] - dAs[tid]);
    // scores: thread -> j = tid&63, i = (tid>>6)+4g
    {
        int j = tid & 63, i0 = tid >> 6;
#pragma unroll
        for (int g = 0; g < 16; ++g) {
            int i = i0 + g * 4;
            float v = 0.f;
            if (j <= i) {
                float d = 0.f;
                const f32x4* cp = (const f32x4*)Cs[i];
                const f32x4* bp = (const f32x4*)Bm[j];
#pragma unroll
                for (int n4 = 0; n4 < 4; ++n4) {
                    f32x4 c = cp[n4], b = bp[n4];
                    d += c.x * b.x + c.y * b.y + c.z * b.z + c.w * b.w;
                }
                v = d * __expf(dAs[i] - dAs[j]) * dts[j];
            }
            sc[i][j] = v;
        }
    }
    __syncthreads();
    // y_intra: thread -> pi=(tid&15)*4, i = (tid>>4) + 16g
    {
        int pi = (tid & 15) * 4;
        int ib = tid >> 4;
#pragma unroll
        for (int g = 0; g < 4; ++g) {
            int i = ib + 16 * g;
            f32x4 a = (f32x4){0.f, 0.f, 0.f, 0.f};
            for (int j = 0; j < 64; ++j) {
                float s = sc[i][j];
                const f32x4 xv = *(const f32x4*)&xs[j][pi];
                a += s * xv;
            }
            u16x4 o; o.x = f2b(a.x); o.y = f2b(a.y); o.z = f2b(a.z); o.w = f2b(a.w);
            *(u16x4*)&y_acc[(tok0 + i) * 1024 + h * 64 + pi] = o;
        }
    }
    // chunk_state[n][p] = sum_k Bm[k][n] * wk[k] * xs[k][p]
    {
        int n = tid >> 4;
        int pi = (tid & 15) * 4;
        f32x4 a = (f32x4){0.f, 0.f, 0.f, 0.f};
        for (int k = 0; k < 64; ++k) {
            float bw = Bm[k][n] * wk[k];
            const f32x4 xv = *(const f32x4*)&xs[k][pi];
            a += bw * xv;
        }
        *(f32x4*)&cstate[(long)bch * 1024 + n * 64 + pi] = a;
    }
}

// ---------------- sequential scan over chunks ----------------
__global__ __launch_bounds__(256) void scan_chunks(const float* __restrict__ cs,
                                                   const float* __restrict__ decay,
                                                   float* __restrict__ hs) {
    int t = blockIdx.x * 256 + threadIdx.x;   // 65536 = b(2) h(4) n(4) p(6)
    int p = t & 63, n = (t >> 6) & 15, h = (t >> 10) & 15, b = t >> 14;
    float state = 0.f;
    for (int c = 0; c < 64; ++c) {
        long idx = (((long)((b * 64 + c) * 16 + h)) * 16 + n) * 64 + p;
        hs[idx] = state;
        state = decay[(b * 64 + c) * 16 + h] * state + cs[idx];
    }
}

// ---------------- y_cross + skip ----------------
__global__ __launch_bounds__(256) void ssm_cross(const u16* __restrict__ proj,
                                                 const float* __restrict__ dAcs,
                                                 const float* __restrict__ hs,
                                                 const u16* __restrict__ y_acc,
                                                 const float* __restrict__ D_param,
                                                 u16* __restrict__ y_pre) {
    int bch = blockIdx.x;
    int bc = bch >> 4, h = bch & 15;
    long tok0 = (long)bc * 64;
    __shared__ float hss[16][64], Cs[64][16], dAs[64];
    int tid = threadIdx.x;
#pragma unroll
    for (int it = 0; it < 4; ++it) {
        int li = it * 256 + tid;
        hss[li >> 6][li & 63] = hs[(long)bch * 1024 + li];
        int i = li >> 4, n = li & 15;
        Cs[i][n] = b2f(proj[(tok0 + i) * PROJ_PAD + 2304 + h * 16 + n]);
    }
    if (tid < 64) dAs[tid] = dAcs[(tok0 + tid) * 16 + h];
    __syncthreads();
    float Dh = D_param[h];
    int pi = (tid & 15) * 4;
    int ib = tid >> 4;
#pragma unroll
    for (int g = 0; g < 4; ++g) {
        int i = ib + 16 * g;
        f32x4 cr = (f32x4){0.f, 0.f, 0.f, 0.f};
#pragma unroll
        for (int n = 0; n < 16; ++n) {
            float c = Cs[i][n];
            cr += c * *(const f32x4*)&hss[n][pi];
        }
        float e = __expf(dAs[i]);
        long off = (tok0 + i) * 1024 + h * 64 + pi;
        u16x4 ya = *(const u16x4*)&y_acc[off];
        u16x4 xv = *(const u16x4*)&proj[(tok0 + i) * PROJ_PAD + h * 64 + pi];
        u16x4 o;
        o.x = f2b(b2f(ya.x) + e * cr.x + b2f(xv.x) * Dh);
        o.y = f2b(b2f(ya.y) + e * cr.y + b2f(xv.y) * Dh);
        o.z = f2b(b2f(ya.z) + e * cr.z + b2f(xv.z) * Dh);
        o.w = f2b(b2f(ya.w) + e * cr.w + b2f(xv.w) * Dh);
        *(u16x4*)&y_pre[off] = o;
    }
}

// ---------------- RMSNorm + SiLU gate (in place on y_pre) ----------------
__global__ __launch_bounds__(256) void norm_gate(const u16* __restrict__ proj,
                                                 const float* __restrict__ norm_w,
                                                 u16* __restrict__ y) {
    long tok = blockIdx.x;
    int tid = threadIdx.x;
    int c0 = tid * 4;
    u16x4 yv = *(const u16x4*)&y[tok * 1024 + c0];
    float v0 = b2f(yv.x), v1 = b2f(yv.y), v2 = b2f(yv.z), v3 = b2f(yv.w);
    float ss = v0 * v0 + v1 * v1 + v2 * v2 + v3 * v3;
    int lane = tid & 63, w = tid >> 6;
#pragma unroll
    for (int d = 32; d > 0; d >>= 1) ss += __shfl_down(ss, d, 64);
    __shared__ float red[4];
    if (lane == 0) red[w] = ss;
    __syncthreads();
    float tot = red[0] + red[1] + red[2] + red[3];
    float inv = rsqrtf(tot * (1.f / 1024.f) + 1e-6f);
    float4 nw = *(const float4*)&norm_w[c0];
    u16x4 zv = *(const u16x4*)&proj[tok * PROJ_PAD + 1024 + c0];
    float z0 = b2f(zv.x), z1 = b2f(zv.y), z2 = b2f(zv.z), z3 = b2f(zv.w);
    u16x4 o;
    o.x = f2b(v0 * inv * nw.x * (z0 / (1.f + __expf(-z0))));
    o.y = f2b(v1 * inv * nw.y * (z1 / (1.f + __expf(-z1))));
    o.z = f2b(v2 * inv * nw.z * (z2 / (1.f + __expf(-z2))));
    o.w = f2b(v3 * inv * nw.w * (z3 / (1.f + __expf(-z3))));
    *(u16x4*)&y[tok * 1024 + c0] = o;
}

extern "C" void kernel_launch(void* const* d_in, const int* in_sizes, int n_in,
                              void* d_out, int out_size, void* d_ws, size_t ws_size,
                              hipStream_t stream) {
    const float* x      = (const float*)d_in[0];
    const float* W_in   = (const float*)d_in[1];
    const float* dt_W   = (const float*)d_in[2];
    const float* dt_b   = (const float*)d_in[3];
    const float* A_log  = (const float*)d_in[4];
    const float* D_par  = (const float*)d_in[5];
    const float* W_out  = (const float*)d_in[6];
    const float* norm_w = (const float*)d_in[7];
    float* out = (float*)d_out;

    char* ws = (char*)d_ws;
    size_t off = 0;
    auto alloc = [&](size_t b) { void* p = ws + off; off += (b + 255) & ~(size_t)255; return p; };
    u16*   x_bf    = (u16*)alloc((size_t)BTOK * DK * 2);         // 33.5 MB
    u16*   win_bf  = (u16*)alloc((size_t)PROJ_PAD * DK * 2);     // 5.5 MB
    u16*   wout_bf = (u16*)alloc((size_t)DK * DK * 2);           // 2.1 MB
    u16*   proj    = (u16*)alloc((size_t)BTOK * PROJ_PAD * 2);   // 88.1 MB
    float* dt      = (float*)alloc((size_t)BTOK * NH * 4);
    float* dAcs    = (float*)alloc((size_t)BTOK * NH * 4);
    float* decay   = (float*)alloc((size_t)NCH * NH * 4);
    float* cstate  = (float*)alloc((size_t)NCH * NH * NS * HD * 4);  // 16.8 MB
    float* hstates = (float*)alloc((size_t)NCH * NH * NS * HD * 4);  // 16.8 MB
    u16*   y_pre   = (u16*)alloc((size_t)BTOK * DK * 2);         // 33.5 MB
    u16*   y_acc   = x_bf;  // alias: x_bf dead after GEMM1 (stream-ordered)

    cast_bf16<<<BTOK * DK / 4 / 256, 256, 0, stream>>>(x, x_bf, BTOK * DK / 4);
    cast_bf16<<<DK * DK / 4 / 256, 256, 0, stream>>>(W_out, wout_bf, DK * DK / 4);
    cast_pad_win<<<PROJ_PAD * DK / 4 / 256, 256, 0, stream>>>(W_in, win_bf);

    gemm_bt<1><<<dim3(128, 21), 256, 0, stream>>>(x_bf, win_bf, nullptr, proj, DK, PROJ_PAD);

    compute_dt<<<NCH, 64, 0, stream>>>(proj, dt_W, dt_b, A_log, dt, dAcs, decay);
    ssm_intra<<<NCH * NH, 256, 0, stream>>>(proj, dt, dAcs, y_acc, cstate);
    scan_chunks<<<256, 256, 0, stream>>>(cstate, decay, hstates);
    ssm_cross<<<NCH * NH, 256, 0, stream>>>(proj, dAcs, hstates, y_acc, D_par, y_pre);
    norm_gate<<<BTOK, 256, 0, stream>>>(proj, norm_w, y_pre);

    gemm_bt<0><<<dim3(128, 8), 256, 0, stream>>>(y_pre, wout_bf, out, nullptr, DK, DK);
}

// Round 2
// 466.611 us; speedup vs baseline: 1.0222x; 1.0222x over previous
//
#include <hip/hip_runtime.h>

typedef unsigned short u16;
typedef __attribute__((ext_vector_type(8))) short short8;   // 8 bf16 (4 VGPRs) MFMA frag
typedef __attribute__((ext_vector_type(4))) float f32x4;
typedef __attribute__((ext_vector_type(4))) unsigned short u16x4;
typedef __attribute__((ext_vector_type(8))) unsigned short u16x8;

#define BTOK 16384      // B*S = 4*4096
#define PROJ_N 2576
#define PROJ_PAD 2688   // 21 * 128
#define DK 1024         // D_MODEL = D_INNER
#define NCH 256         // B * nChunks = 4*64
#define NH 16
#define HD 64
#define NS 16           // D_STATE

__device__ __forceinline__ float b2f(u16 b) {
    union { unsigned int u; float f; } v; v.u = ((unsigned int)b) << 16; return v.f;
}
__device__ __forceinline__ u16 f2b(float f) {
    union { float f; unsigned int u; } v; v.f = f;
    unsigned int r = v.u + 0x7fffu + ((v.u >> 16) & 1u);
    return (u16)(r >> 16);
}
// async global->LDS, 16B/lane; LDS dest is wave-uniform base + lane*16
__device__ __forceinline__ void gl_lds16(const u16* g, u16* l) {
    __builtin_amdgcn_global_load_lds((__attribute__((address_space(1))) void*)g,
                                     (__attribute__((address_space(3))) void*)l,
                                     16, 0, 0);
}

// ---------------- casts ----------------
__global__ __launch_bounds__(256) void cast_bf16(const float* __restrict__ s,
                                                 u16* __restrict__ d, int n4) {
    int t = blockIdx.x * 256 + threadIdx.x;
    if (t < n4) {
        float4 v = ((const float4*)s)[t];
        u16x4 o; o.x = f2b(v.x); o.y = f2b(v.y); o.z = f2b(v.z); o.w = f2b(v.w);
        ((u16x4*)d)[t] = o;
    }
}

__global__ __launch_bounds__(256) void cast_pad_win(const float* __restrict__ s,
                                                    u16* __restrict__ d) {
    int t = blockIdx.x * 256 + threadIdx.x;
    int i4 = t * 4;
    float4 v = make_float4(0.f, 0.f, 0.f, 0.f);
    if (i4 < PROJ_N * DK) v = ((const float4*)s)[t];
    u16x4 o; o.x = f2b(v.x); o.y = f2b(v.y); o.z = f2b(v.z); o.w = f2b(v.w);
    ((u16x4*)d)[t] = o;
}

// ---------------- GEMM: C[M,N] = A[M,K] * B[N,K]^T, bf16 in, fp32 acc ----------------
// m97 structure: global_load_lds width=16, unpadded LDS, 128x128 tile, 4 waves 64x64.
// grid: x = bn (N tiles), y = bm (M tiles) so A-tile-sharing blocks are adjacent.
template <int OUT_BF16>
__global__ __launch_bounds__(256) void gemm_bt(const u16* __restrict__ A,
                                               const u16* __restrict__ B,
                                               float* __restrict__ Cf,
                                               u16* __restrict__ Cb,
                                               int K, int ldc) {
    __shared__ u16 As[128 * 64];
    __shared__ u16 Bs[128 * 64];
    const int tid = threadIdx.x;
    const int bn = blockIdx.x, bm = blockIdx.y;
    const int wave = tid >> 6, lane = tid & 63;
    const int wm = (wave >> 1) * 64, wn = (wave & 1) * 64;
    const int m_l = lane & 15, quad = lane >> 4;

    f32x4 acc[4][4];
#pragma unroll
    for (int i = 0; i < 4; ++i)
#pragma unroll
        for (int j = 0; j < 4; ++j) acc[i][j] = (f32x4){0.f, 0.f, 0.f, 0.f};

    const u16* Ab = A + (long)bm * 128 * K;
    const u16* Bb = B + (long)bn * 128 * K;

    for (int k0 = 0; k0 < K; k0 += 64) {
#pragma unroll
        for (int it = 0; it < 4; ++it) {
            int li = it * 256 + tid;          // chunk id 0..1023; lane l -> base + l*16
            int r = li >> 3, c8 = (li & 7) * 8;
            u16* lbase = &As[(it * 256 + wave * 64) * 8];   // wave-uniform
            gl_lds16(Ab + (long)r * K + k0 + c8, lbase);
            u16* lbaseB = &Bs[(it * 256 + wave * 64) * 8];
            gl_lds16(Bb + (long)r * K + k0 + c8, lbaseB);
        }
        __syncthreads();
#pragma unroll
        for (int ks = 0; ks < 2; ++ks) {
            const int kc = ks * 32 + quad * 8;
            short8 af[4], bf[4];
#pragma unroll
            for (int i = 0; i < 4; ++i) af[i] = *(const short8*)(&As[(wm + i * 16 + m_l) * 64 + kc]);
#pragma unroll
            for (int j = 0; j < 4; ++j) bf[j] = *(const short8*)(&Bs[(wn + j * 16 + m_l) * 64 + kc]);
#pragma unroll
            for (int i = 0; i < 4; ++i)
#pragma unroll
                for (int j = 0; j < 4; ++j)
                    acc[i][j] = __builtin_amdgcn_mfma_f32_16x16x32_bf16(af[i], bf[j], acc[i][j], 0, 0, 0);
        }
        __syncthreads();
    }
    // C/D layout: col=lane&15, row=quad*4+reg (m89/m91 verified)
#pragma unroll
    for (int i = 0; i < 4; ++i) {
        int row_base = bm * 128 + wm + i * 16 + quad * 4;
#pragma unroll
        for (int j = 0; j < 4; ++j) {
            int col = bn * 128 + wn + j * 16 + m_l;
#pragma unroll
            for (int r = 0; r < 4; ++r) {
                float v = acc[i][j][r];
                long off = (long)(row_base + r) * ldc + col;
                if (OUT_BF16) Cb[off] = f2b(v);
                else          Cf[off] = v;
            }
        }
    }
}

// ---------------- dt: softplus(dt_low @ dt_W^T + dt_b), dA cumsum per chunk ----------------
__global__ __launch_bounds__(64) void compute_dt(const u16* __restrict__ proj,
                                                 const float* __restrict__ dt_W,
                                                 const float* __restrict__ dt_b,
                                                 const float* __restrict__ A_log,
                                                 float* __restrict__ dt,
                                                 float* __restrict__ dAcs,
                                                 float* __restrict__ decay) {
    int bc = blockIdx.x;
    int i = threadIdx.x;
    long tok = (long)bc * 64 + i;
    float low[16];
#pragma unroll
    for (int r = 0; r < 16; ++r) low[r] = b2f(proj[tok * PROJ_PAD + 2560 + r]);
#pragma unroll
    for (int h = 0; h < 16; ++h) {
        float a = dt_b[h];
#pragma unroll
        for (int r = 0; r < 16; ++r) a += low[r] * dt_W[h * 16 + r];
        float d = (a > 20.f) ? a : log1pf(__expf(a));
        float dA = -__expf(A_log[h]) * d;
        float cs = dA;
#pragma unroll
        for (int off = 1; off < 64; off <<= 1) {
            float o = __shfl_up(cs, off, 64);
            if (i >= off) cs += o;
        }
        dt[tok * 16 + h] = d;
        dAcs[tok * 16 + h] = cs;
        if (i == 63) decay[bc * 16 + h] = __expf(cs);
    }
}

// ---------------- intra-chunk: scores (VALU fp32 -> bf16 hi/lo), y_intra + cstate via MFMA ----
__global__ __launch_bounds__(256) void ssm_intra(const u16* __restrict__ proj,
                                                 const float* __restrict__ dt,
                                                 const float* __restrict__ dAcs,
                                                 u16* __restrict__ y_acc,
                                                 float* __restrict__ cstate) {
    int bch = blockIdx.x;             // (b*64+c)*16 + h
    int bc = bch >> 4, h = bch & 15;
    long tok0 = (long)bc * 64;
    __shared__ float Cs[64][16], Bm[64][16];
    __shared__ u16 Sh[64][64], Sl[64][64];   // scores hi/lo, [i][j] (A-operand layout)
    __shared__ u16 Xt[64][64];               // X^T: [p][j]   (B-operand for y_intra)
    __shared__ u16 Wh[64][64], Wl[64][64];   // (w*X)^T hi/lo: [p][k] (B-operand for cstate)
    __shared__ u16 Bt[16][64];               // B^T: [n][k]   (A-operand for cstate)
    __shared__ float dts[64], dAs[64], wk[64];
    const int tid = threadIdx.x;
    const int wave = tid >> 6, lane = tid & 63;
    const int m_l = lane & 15, quad = lane >> 4;

    if (tid < 64) {
        dts[tid] = dt[(tok0 + tid) * 16 + h];
        dAs[tid] = dAcs[(tok0 + tid) * 16 + h];
    }
    if (tid < 64) wk[tid] = dts[tid] * __expf(dAs[63] - dAs[tid]);   // wave 0 only: no barrier needed
#pragma unroll
    for (int it = 0; it < 4; ++it) {
        int li = it * 256 + tid;
        int i = li >> 4, n = li & 15;
        u16 cb = proj[(tok0 + i) * PROJ_PAD + 2304 + h * 16 + n];
        u16 bb = proj[(tok0 + i) * PROJ_PAD + 2048 + h * 16 + n];
        Cs[i][n] = b2f(cb);
        Bm[i][n] = b2f(bb);
        Bt[n][i] = bb;
    }
    __syncthreads();   // wk + C/B ready
    // X load: transpose + w-scale (hi/lo split keeps full fp32 precision through MFMA)
#pragma unroll
    for (int it = 0; it < 2; ++it) {
        int li = it * 256 + tid;
        int j = li & 63, p0 = (li >> 6) * 8;
        u16x8 xv = *(const u16x8*)&proj[(tok0 + j) * PROJ_PAD + h * 64 + p0];
        float w = wk[j];
#pragma unroll
        for (int t = 0; t < 8; ++t) {
            u16 xb = xv[t];
            Xt[p0 + t][j] = xb;
            float v = w * b2f(xb);
            u16 hi = f2b(v);
            Wh[p0 + t][j] = hi;
            Wl[p0 + t][j] = f2b(v - b2f(hi));
        }
    }
    // scores (fp32 VALU): S[i][j] = (C_i . B_j) * exp(dA_i - dA_j) * dt_j, causal
    {
        int j = tid & 63, i0 = tid >> 6;
#pragma unroll
        for (int g = 0; g < 16; ++g) {
            int i = i0 + g * 4;
            float v = 0.f;
            if (j <= i) {
                float d = 0.f;
                const f32x4* cp = (const f32x4*)Cs[i];
                const f32x4* bp = (const f32x4*)Bm[j];
#pragma unroll
                for (int n4 = 0; n4 < 4; ++n4) {
                    f32x4 c = cp[n4], b = bp[n4];
                    d += c.x * b.x + c.y * b.y + c.z * b.z + c.w * b.w;
                }
                v = d * __expf(dAs[i] - dAs[j]) * dts[j];
            }
            u16 hi = f2b(v);
            Sh[i][j] = hi;
            Sl[i][j] = f2b(v - b2f(hi));
        }
    }
    __syncthreads();
    // y_intra: wave w owns i-tile w (16 rows), 4 p-tiles, K=64 over j, hi+lo
    {
        f32x4 yv[4];
#pragma unroll
        for (int jt = 0; jt < 4; ++jt) yv[jt] = (f32x4){0.f, 0.f, 0.f, 0.f};
#pragma unroll
        for (int ks = 0; ks < 2; ++ks) {
            int kc = ks * 32 + quad * 8;
            short8 ah = *(const short8*)&Sh[wave * 16 + m_l][kc];
            short8 al = *(const short8*)&Sl[wave * 16 + m_l][kc];
#pragma unroll
            for (int jt = 0; jt < 4; ++jt) {
                short8 bx = *(const short8*)&Xt[jt * 16 + m_l][kc];
                yv[jt] = __builtin_amdgcn_mfma_f32_16x16x32_bf16(ah, bx, yv[jt], 0, 0, 0);
                yv[jt] = __builtin_amdgcn_mfma_f32_16x16x32_bf16(al, bx, yv[jt], 0, 0, 0);
            }
        }
#pragma unroll
        for (int jt = 0; jt < 4; ++jt)
#pragma unroll
            for (int r = 0; r < 4; ++r) {
                int i = wave * 16 + quad * 4 + r;
                int p = jt * 16 + m_l;
                y_acc[(tok0 + i) * 1024 + h * 64 + p] = f2b(yv[jt][r]);
            }
    }
    // cstate: wave w owns p-tile w; out [n=16][p=16], K=64 over tokens, hi+lo
    {
        f32x4 cacc = (f32x4){0.f, 0.f, 0.f, 0.f};
#pragma unroll
        for (int ks = 0; ks < 2; ++ks) {
            int kc = ks * 32 + quad * 8;
            short8 a = *(const short8*)&Bt[m_l][kc];
            short8 bh = *(const short8*)&Wh[wave * 16 + m_l][kc];
            short8 bl = *(const short8*)&Wl[wave * 16 + m_l][kc];
            cacc = __builtin_amdgcn_mfma_f32_16x16x32_bf16(a, bh, cacc, 0, 0, 0);
            cacc = __builtin_amdgcn_mfma_f32_16x16x32_bf16(a, bl, cacc, 0, 0, 0);
        }
#pragma unroll
        for (int r = 0; r < 4; ++r) {
            int n = quad * 4 + r;
            int p = wave * 16 + m_l;
            cstate[(long)bch * 1024 + n * 64 + p] = cacc[r];
        }
    }
}

// ---------------- sequential scan over chunks ----------------
__global__ __launch_bounds__(256) void scan_chunks(const float* __restrict__ cs,
                                                   const float* __restrict__ decay,
                                                   float* __restrict__ hs) {
    int t = blockIdx.x * 256 + threadIdx.x;
    int p = t & 63, n = (t >> 6) & 15, h = (t >> 10) & 15, b = t >> 14;
    float state = 0.f;
    for (int c = 0; c < 64; ++c) {
        long idx = (((long)((b * 64 + c) * 16 + h)) * 16 + n) * 64 + p;
        hs[idx] = state;
        state = decay[(b * 64 + c) * 16 + h] * state + cs[idx];
    }
}

// ---------------- y_cross + skip ----------------
__global__ __launch_bounds__(256) void ssm_cross(const u16* __restrict__ proj,
                                                 const float* __restrict__ dAcs,
                                                 const float* __restrict__ hs,
                                                 const u16* __restrict__ y_acc,
                                                 const float* __restrict__ D_param,
                                                 u16* __restrict__ y_pre) {
    int bch = blockIdx.x;
    int bc = bch >> 4, h = bch & 15;
    long tok0 = (long)bc * 64;
    __shared__ float hss[16][64], Cs[64][16], dAs[64];
    int tid = threadIdx.x;
#pragma unroll
    for (int it = 0; it < 4; ++it) {
        int li = it * 256 + tid;
        hss[li >> 6][li & 63] = hs[(long)bch * 1024 + li];
        int i = li >> 4, n = li & 15;
        Cs[i][n] = b2f(proj[(tok0 + i) * PROJ_PAD + 2304 + h * 16 + n]);
    }
    if (tid < 64) dAs[tid] = dAcs[(tok0 + tid) * 16 + h];
    __syncthreads();
    float Dh = D_param[h];
    int pi = (tid & 15) * 4;
    int ib = tid >> 4;
#pragma unroll
    for (int g = 0; g < 4; ++g) {
        int i = ib + 16 * g;
        f32x4 cr = (f32x4){0.f, 0.f, 0.f, 0.f};
#pragma unroll
        for (int n = 0; n < 16; ++n) {
            float c = Cs[i][n];
            cr += c * *(const f32x4*)&hss[n][pi];
        }
        float e = __expf(dAs[i]);
        long off = (tok0 + i) * 1024 + h * 64 + pi;
        u16x4 ya = *(const u16x4*)&y_acc[off];
        u16x4 xv = *(const u16x4*)&proj[(tok0 + i) * PROJ_PAD + h * 64 + pi];
        u16x4 o;
        o.x = f2b(b2f(ya.x) + e * cr.x + b2f(xv.x) * Dh);
        o.y = f2b(b2f(ya.y) + e * cr.y + b2f(xv.y) * Dh);
        o.z = f2b(b2f(ya.z) + e * cr.z + b2f(xv.z) * Dh);
        o.w = f2b(b2f(ya.w) + e * cr.w + b2f(xv.w) * Dh);
        *(u16x4*)&y_pre[off] = o;
    }
}

// ---------------- RMSNorm + SiLU gate (in place on y_pre) ----------------
__global__ __launch_bounds__(256) void norm_gate(const u16* __restrict__ proj,
                                                 const float* __restrict__ norm_w,
                                                 u16* __restrict__ y) {
    long tok = blockIdx.x;
    int tid = threadIdx.x;
    int c0 = tid * 4;
    u16x4 yv = *(const u16x4*)&y[tok * 1024 + c0];
    float v0 = b2f(yv.x), v1 = b2f(yv.y), v2 = b2f(yv.z), v3 = b2f(yv.w);
    float ss = v0 * v0 + v1 * v1 + v2 * v2 + v3 * v3;
    int lane = tid & 63, w = tid >> 6;
#pragma unroll
    for (int d = 32; d > 0; d >>= 1) ss += __shfl_down(ss, d, 64);
    __shared__ float red[4];
    if (lane == 0) red[w] = ss;
    __syncthreads();
    float tot = red[0] + red[1] + red[2] + red[3];
    float inv = rsqrtf(tot * (1.f / 1024.f) + 1e-6f);
    float4 nw = *(const float4*)&norm_w[c0];
    u16x4 zv = *(const u16x4*)&proj[tok * PROJ_PAD + 1024 + c0];
    float z0 = b2f(zv.x), z1 = b2f(zv.y), z2 = b2f(zv.z), z3 = b2f(zv.w);
    u16x4 o;
    o.x = f2b(v0 * inv * nw.x * (z0 / (1.f + __expf(-z0))));
    o.y = f2b(v1 * inv * nw.y * (z1 / (1.f + __expf(-z1))));
    o.z = f2b(v2 * inv * nw.z * (z2 / (1.f + __expf(-z2))));
    o.w = f2b(v3 * inv * nw.w * (z3 / (1.f + __expf(-z3))));
    *(u16x4*)&y[tok * 1024 + c0] = o;
}

extern "C" void kernel_launch(void* const* d_in, const int* in_sizes, int n_in,
                              void* d_out, int out_size, void* d_ws, size_t ws_size,
                              hipStream_t stream) {
    const float* x      = (const float*)d_in[0];
    const float* dt_W   = (const float*)d_in[2];
    const float* dt_b   = (const float*)d_in[3];
    const float* A_log  = (const float*)d_in[4];
    const float* D_par  = (const float*)d_in[5];
    const float* W_out  = (const float*)d_in[6];
    const float* norm_w = (const float*)d_in[7];
    const float* W_in   = (const float*)d_in[1];
    float* out = (float*)d_out;

    char* ws = (char*)d_ws;
    size_t off = 0;
    auto alloc = [&](size_t b) { void* p = ws + off; off += (b + 255) & ~(size_t)255; return p; };
    u16*   x_bf    = (u16*)alloc((size_t)BTOK * DK * 2);
    u16*   win_bf  = (u16*)alloc((size_t)PROJ_PAD * DK * 2);
    u16*   wout_bf = (u16*)alloc((size_t)DK * DK * 2);
    u16*   proj    = (u16*)alloc((size_t)BTOK * PROJ_PAD * 2);
    float* dt      = (float*)alloc((size_t)BTOK * NH * 4);
    float* dAcs    = (float*)alloc((size_t)BTOK * NH * 4);
    float* decay   = (float*)alloc((size_t)NCH * NH * 4);
    float* cstate  = (float*)alloc((size_t)NCH * NH * NS * HD * 4);
    float* hstates = (float*)alloc((size_t)NCH * NH * NS * HD * 4);
    u16*   y_pre   = (u16*)alloc((size_t)BTOK * DK * 2);
    u16*   y_acc   = x_bf;  // alias: x_bf dead after GEMM1 (stream-ordered)

    cast_bf16<<<BTOK * DK / 4 / 256, 256, 0, stream>>>(x, x_bf, BTOK * DK / 4);
    cast_bf16<<<DK * DK / 4 / 256, 256, 0, stream>>>(W_out, wout_bf, DK * DK / 4);
    cast_pad_win<<<PROJ_PAD * DK / 4 / 256, 256, 0, stream>>>(W_in, win_bf);

    gemm_bt<1><<<dim3(21, 128), 256, 0, stream>>>(x_bf, win_bf, nullptr, proj, DK, PROJ_PAD);

    compute_dt<<<NCH, 64, 0, stream>>>(proj, dt_W, dt_b, A_log, dt, dAcs, decay);
    ssm_intra<<<NCH * NH, 256, 0, stream>>>(proj, dt, dAcs, y_acc, cstate);
    scan_chunks<<<256, 256, 0, stream>>>(cstate, decay, hstates);
    ssm_cross<<<NCH * NH, 256, 0, stream>>>(proj, dAcs, hstates, y_acc, D_par, y_pre);
    norm_gate<<<BTOK, 256, 0, stream>>>(proj, norm_w, y_pre);

    gemm_bt<0><<<dim3(8, 128), 256, 0, stream>>>(y_pre, wout_bf, out, nullptr, DK, DK);
}

// Round 3
// 412.509 us; speedup vs baseline: 1.1563x; 1.1312x over previous
//
#include <hip/hip_runtime.h>

typedef unsigned short u16;
typedef __attribute__((ext_vector_type(8))) short short8;   // 8 bf16 (4 VGPRs) MFMA frag
typedef __attribute__((ext_vector_type(4))) float f32x4;
typedef __attribute__((ext_vector_type(4))) unsigned short u16x4;
typedef __attribute__((ext_vector_type(8))) unsigned short u16x8;

#define BTOK 16384      // B*S = 4*4096
#define PROJ_N 2576
#define PROJ_PAD 2688   // 21 * 128
#define DK 1024         // D_MODEL = D_INNER
#define NCH 256         // B * nChunks = 4*64
#define NH 16
#define HD 64
#define NS 16           // D_STATE

__device__ __forceinline__ float b2f(u16 b) {
    union { unsigned int u; float f; } v; v.u = ((unsigned int)b) << 16; return v.f;
}
__device__ __forceinline__ u16 f2b(float f) {
    union { float f; unsigned int u; } v; v.f = f;
    unsigned int r = v.u + 0x7fffu + ((v.u >> 16) & 1u);
    return (u16)(r >> 16);
}
// async global->LDS, 16B/lane; LDS dest is wave-uniform base + lane*16 (global addr is per-lane)
__device__ __forceinline__ void gl_lds16(const u16* g, u16* l) {
    __builtin_amdgcn_global_load_lds((__attribute__((address_space(1))) void*)g,
                                     (__attribute__((address_space(3))) void*)l,
                                     16, 0, 0);
}

// ---------------- casts ----------------
__global__ __launch_bounds__(256) void cast_bf16(const float* __restrict__ s,
                                                 u16* __restrict__ d, int n4) {
    int t = blockIdx.x * 256 + threadIdx.x;
    if (t < n4) {
        float4 v = ((const float4*)s)[t];
        u16x4 o; o.x = f2b(v.x); o.y = f2b(v.y); o.z = f2b(v.z); o.w = f2b(v.w);
        ((u16x4*)d)[t] = o;
    }
}

__global__ __launch_bounds__(256) void cast_pad_win(const float* __restrict__ s,
                                                    u16* __restrict__ d) {
    int t = blockIdx.x * 256 + threadIdx.x;
    int i4 = t * 4;
    float4 v = make_float4(0.f, 0.f, 0.f, 0.f);
    if (i4 < PROJ_N * DK) v = ((const float4*)s)[t];
    u16x4 o; o.x = f2b(v.x); o.y = f2b(v.y); o.z = f2b(v.z); o.w = f2b(v.w);
    ((u16x4*)d)[t] = o;
}

// ---------------- GEMM: C[M,N] = A[M,K] * B[N,K]^T, bf16 in, fp32 acc ----------------
// global_load_lds width=16 staging with XOR-swizzled LDS layout:
//   16B chunk (row, k8) lives at LDS 16B-offset row*8 + (k8 ^ (row&7)).
//   Staging permutes per-lane GLOBAL addresses (legal: only LDS side is rigid);
//   fragment ds_read_b128 then spreads evenly over all 32 banks.
// grid: x = bm (M tiles, fastest) — R1-measured better L2 ordering.
template <int OUT_BF16>
__global__ __launch_bounds__(256) void gemm_bt(const u16* __restrict__ A,
                                               const u16* __restrict__ B,
                                               float* __restrict__ Cf,
                                               u16* __restrict__ Cb,
                                               int K, int ldc) {
    __shared__ u16 As[128 * 64];
    __shared__ u16 Bs[128 * 64];
    const int tid = threadIdx.x;
    const int bm = blockIdx.x, bn = blockIdx.y;
    const int wave = tid >> 6, lane = tid & 63;
    const int wm = (wave >> 1) * 64, wn = (wave & 1) * 64;
    const int m_l = lane & 15, quad = lane >> 4;

    f32x4 acc[4][4];
#pragma unroll
    for (int i = 0; i < 4; ++i)
#pragma unroll
        for (int j = 0; j < 4; ++j) acc[i][j] = (f32x4){0.f, 0.f, 0.f, 0.f};

    const u16* Ab = A + (long)bm * 128 * K;
    const u16* Bb = B + (long)bn * 128 * K;

    // per-thread staging decode (li = chunk id 0..1023): row = li>>3, slot = li&7,
    // source k8 = slot ^ (row&7)  -> global offset row*K + k8*8
    for (int k0 = 0; k0 < K; k0 += 64) {
#pragma unroll
        for (int it = 0; it < 4; ++it) {
            int li = it * 256 + tid;
            int r = li >> 3;
            int k8 = (li & 7) ^ (r & 7);
            u16* lbase = &As[(it * 256 + wave * 64) * 8];   // wave-uniform
            gl_lds16(Ab + (long)r * K + k0 + k8 * 8, lbase);
            u16* lbaseB = &Bs[(it * 256 + wave * 64) * 8];
            gl_lds16(Bb + (long)r * K + k0 + k8 * 8, lbaseB);
        }
        __syncthreads();
#pragma unroll
        for (int ks = 0; ks < 2; ++ks) {
            const int k8 = ks * 4 + quad;
            const int slot = k8 ^ (m_l & 7);     // row&7 == m_l&7 (tile rows are 16-aligned)
            short8 af[4], bf[4];
#pragma unroll
            for (int i = 0; i < 4; ++i) af[i] = *(const short8*)(&As[(wm + i * 16 + m_l) * 64 + slot * 8]);
#pragma unroll
            for (int j = 0; j < 4; ++j) bf[j] = *(const short8*)(&Bs[(wn + j * 16 + m_l) * 64 + slot * 8]);
#pragma unroll
            for (int i = 0; i < 4; ++i)
#pragma unroll
                for (int j = 0; j < 4; ++j)
                    acc[i][j] = __builtin_amdgcn_mfma_f32_16x16x32_bf16(af[i], bf[j], acc[i][j], 0, 0, 0);
        }
        __syncthreads();
    }
    // C/D layout: col=lane&15, row=quad*4+reg (m89/m91 verified)
#pragma unroll
    for (int i = 0; i < 4; ++i) {
        int row_base = bm * 128 + wm + i * 16 + quad * 4;
#pragma unroll
        for (int j = 0; j < 4; ++j) {
            int col = bn * 128 + wn + j * 16 + m_l;
#pragma unroll
            for (int r = 0; r < 4; ++r) {
                float v = acc[i][j][r];
                long off = (long)(row_base + r) * ldc + col;
                if (OUT_BF16) Cb[off] = f2b(v);
                else          Cf[off] = v;
            }
        }
    }
}

// ---------------- dt: softplus(dt_low @ dt_W^T + dt_b), dA cumsum per chunk ----------------
__global__ __launch_bounds__(64) void compute_dt(const u16* __restrict__ proj,
                                                 const float* __restrict__ dt_W,
                                                 const float* __restrict__ dt_b,
                                                 const float* __restrict__ A_log,
                                                 float* __restrict__ dt,
                                                 float* __restrict__ dAcs,
                                                 float* __restrict__ decay) {
    int bc = blockIdx.x;
    int i = threadIdx.x;
    long tok = (long)bc * 64 + i;
    float low[16];
#pragma unroll
    for (int r = 0; r < 16; ++r) low[r] = b2f(proj[tok * PROJ_PAD + 2560 + r]);
#pragma unroll
    for (int h = 0; h < 16; ++h) {
        float a = dt_b[h];
#pragma unroll
        for (int r = 0; r < 16; ++r) a += low[r] * dt_W[h * 16 + r];
        float d = (a > 20.f) ? a : log1pf(__expf(a));
        float dA = -__expf(A_log[h]) * d;
        float cs = dA;
#pragma unroll
        for (int off = 1; off < 64; off <<= 1) {
            float o = __shfl_up(cs, off, 64);
            if (i >= off) cs += o;
        }
        dt[tok * 16 + h] = d;
        dAcs[tok * 16 + h] = cs;
        if (i == 63) decay[bc * 16 + h] = __expf(cs);
    }
}

// ---------------- intra-chunk: scores (VALU fp32 -> bf16 hi/lo), y_intra + cstate via MFMA ----
__global__ __launch_bounds__(256) void ssm_intra(const u16* __restrict__ proj,
                                                 const float* __restrict__ dt,
                                                 const float* __restrict__ dAcs,
                                                 u16* __restrict__ y_acc,
                                                 float* __restrict__ cstate) {
    int bch = blockIdx.x;             // (b*64+c)*16 + h
    int bc = bch >> 4, h = bch & 15;
    long tok0 = (long)bc * 64;
    __shared__ float Cs[64][16], Bm[64][16];
    __shared__ u16 Sh[64][64], Sl[64][64];   // scores hi/lo, [i][j] (A-operand layout)
    __shared__ u16 Xt[64][64];               // X^T: [p][j]   (B-operand for y_intra)
    __shared__ u16 Wh[64][64], Wl[64][64];   // (w*X)^T hi/lo: [p][k] (B-operand for cstate)
    __shared__ u16 Bt[16][64];               // B^T: [n][k]   (A-operand for cstate)
    __shared__ float dts[64], dAs[64], wk[64];
    const int tid = threadIdx.x;
    const int wave = tid >> 6, lane = tid & 63;
    const int m_l = lane & 15, quad = lane >> 4;

    if (tid < 64) {
        dts[tid] = dt[(tok0 + tid) * 16 + h];
        dAs[tid] = dAcs[(tok0 + tid) * 16 + h];
    }
    if (tid < 64) wk[tid] = dts[tid] * __expf(dAs[63] - dAs[tid]);   // wave 0 only: no barrier needed
#pragma unroll
    for (int it = 0; it < 4; ++it) {
        int li = it * 256 + tid;
        int i = li >> 4, n = li & 15;
        u16 cb = proj[(tok0 + i) * PROJ_PAD + 2304 + h * 16 + n];
        u16 bb = proj[(tok0 + i) * PROJ_PAD + 2048 + h * 16 + n];
        Cs[i][n] = b2f(cb);
        Bm[i][n] = b2f(bb);
        Bt[n][i] = bb;
    }
    __syncthreads();   // wk + C/B ready
    // X load: transpose + w-scale (hi/lo split keeps full fp32 precision through MFMA)
#pragma unroll
    for (int it = 0; it < 2; ++it) {
        int li = it * 256 + tid;
        int j = li & 63, p0 = (li >> 6) * 8;
        u16x8 xv = *(const u16x8*)&proj[(tok0 + j) * PROJ_PAD + h * 64 + p0];
        float w = wk[j];
#pragma unroll
        for (int t = 0; t < 8; ++t) {
            u16 xb = xv[t];
            Xt[p0 + t][j] = xb;
            float v = w * b2f(xb);
            u16 hi = f2b(v);
            Wh[p0 + t][j] = hi;
            Wl[p0 + t][j] = f2b(v - b2f(hi));
        }
    }
    // scores (fp32 VALU): S[i][j] = (C_i . B_j) * exp(dA_i - dA_j) * dt_j, causal
    {
        int j = tid & 63, i0 = tid >> 6;
#pragma unroll
        for (int g = 0; g < 16; ++g) {
            int i = i0 + g * 4;
            float v = 0.f;
            if (j <= i) {
                float d = 0.f;
                const f32x4* cp = (const f32x4*)Cs[i];
                const f32x4* bp = (const f32x4*)Bm[j];
#pragma unroll
                for (int n4 = 0; n4 < 4; ++n4) {
                    f32x4 c = cp[n4], b = bp[n4];
                    d += c.x * b.x + c.y * b.y + c.z * b.z + c.w * b.w;
                }
                v = d * __expf(dAs[i] - dAs[j]) * dts[j];
            }
            u16 hi = f2b(v);
            Sh[i][j] = hi;
            Sl[i][j] = f2b(v - b2f(hi));
        }
    }
    __syncthreads();
    // y_intra: wave w owns i-tile w (16 rows), 4 p-tiles, K=64 over j, hi+lo
    {
        f32x4 yv[4];
#pragma unroll
        for (int jt = 0; jt < 4; ++jt) yv[jt] = (f32x4){0.f, 0.f, 0.f, 0.f};
#pragma unroll
        for (int ks = 0; ks < 2; ++ks) {
            int kc = ks * 32 + quad * 8;
            short8 ah = *(const short8*)&Sh[wave * 16 + m_l][kc];
            short8 al = *(const short8*)&Sl[wave * 16 + m_l][kc];
#pragma unroll
            for (int jt = 0; jt < 4; ++jt) {
                short8 bx = *(const short8*)&Xt[jt * 16 + m_l][kc];
                yv[jt] = __builtin_amdgcn_mfma_f32_16x16x32_bf16(ah, bx, yv[jt], 0, 0, 0);
                yv[jt] = __builtin_amdgcn_mfma_f32_16x16x32_bf16(al, bx, yv[jt], 0, 0, 0);
            }
        }
#pragma unroll
        for (int jt = 0; jt < 4; ++jt)
#pragma unroll
            for (int r = 0; r < 4; ++r) {
                int i = wave * 16 + quad * 4 + r;
                int p = jt * 16 + m_l;
                y_acc[(tok0 + i) * 1024 + h * 64 + p] = f2b(yv[jt][r]);
            }
    }
    // cstate: wave w owns p-tile w; out [n=16][p=16], K=64 over tokens, hi+lo
    {
        f32x4 cacc = (f32x4){0.f, 0.f, 0.f, 0.f};
#pragma unroll
        for (int ks = 0; ks < 2; ++ks) {
            int kc = ks * 32 + quad * 8;
            short8 a = *(const short8*)&Bt[m_l][kc];
            short8 bh = *(const short8*)&Wh[wave * 16 + m_l][kc];
            short8 bl = *(const short8*)&Wl[wave * 16 + m_l][kc];
            cacc = __builtin_amdgcn_mfma_f32_16x16x32_bf16(a, bh, cacc, 0, 0, 0);
            cacc = __builtin_amdgcn_mfma_f32_16x16x32_bf16(a, bl, cacc, 0, 0, 0);
        }
#pragma unroll
        for (int r = 0; r < 4; ++r) {
            int n = quad * 4 + r;
            int p = wave * 16 + m_l;
            cstate[(long)bch * 1024 + n * 64 + p] = cacc[r];
        }
    }
}

// ---------------- sequential scan over chunks ----------------
__global__ __launch_bounds__(256) void scan_chunks(const float* __restrict__ cs,
                                                   const float* __restrict__ decay,
                                                   float* __restrict__ hs) {
    int t = blockIdx.x * 256 + threadIdx.x;
    int p = t & 63, n = (t >> 6) & 15, h = (t >> 10) & 15, b = t >> 14;
    float state = 0.f;
    for (int c = 0; c < 64; ++c) {
        long idx = (((long)((b * 64 + c) * 16 + h)) * 16 + n) * 64 + p;
        hs[idx] = state;
        state = decay[(b * 64 + c) * 16 + h] * state + cs[idx];
    }
}

// ---------------- y_cross + skip ----------------
__global__ __launch_bounds__(256) void ssm_cross(const u16* __restrict__ proj,
                                                 const float* __restrict__ dAcs,
                                                 const float* __restrict__ hs,
                                                 const u16* __restrict__ y_acc,
                                                 const float* __restrict__ D_param,
                                                 u16* __restrict__ y_pre) {
    int bch = blockIdx.x;
    int bc = bch >> 4, h = bch & 15;
    long tok0 = (long)bc * 64;
    __shared__ float hss[16][64], Cs[64][16], dAs[64];
    int tid = threadIdx.x;
#pragma unroll
    for (int it = 0; it < 4; ++it) {
        int li = it * 256 + tid;
        hss[li >> 6][li & 63] = hs[(long)bch * 1024 + li];
        int i = li >> 4, n = li & 15;
        Cs[i][n] = b2f(proj[(tok0 + i) * PROJ_PAD + 2304 + h * 16 + n]);
    }
    if (tid < 64) dAs[tid] = dAcs[(tok0 + tid) * 16 + h];
    __syncthreads();
    float Dh = D_param[h];
    int pi = (tid & 15) * 4;
    int ib = tid >> 4;
#pragma unroll
    for (int g = 0; g < 4; ++g) {
        int i = ib + 16 * g;
        f32x4 cr = (f32x4){0.f, 0.f, 0.f, 0.f};
#pragma unroll
        for (int n = 0; n < 16; ++n) {
            float c = Cs[i][n];
            cr += c * *(const f32x4*)&hss[n][pi];
        }
        float e = __expf(dAs[i]);
        long off = (tok0 + i) * 1024 + h * 64 + pi;
        u16x4 ya = *(const u16x4*)&y_acc[off];
        u16x4 xv = *(const u16x4*)&proj[(tok0 + i) * PROJ_PAD + h * 64 + pi];
        u16x4 o;
        o.x = f2b(b2f(ya.x) + e * cr.x + b2f(xv.x) * Dh);
        o.y = f2b(b2f(ya.y) + e * cr.y + b2f(xv.y) * Dh);
        o.z = f2b(b2f(ya.z) + e * cr.z + b2f(xv.z) * Dh);
        o.w = f2b(b2f(ya.w) + e * cr.w + b2f(xv.w) * Dh);
        *(u16x4*)&y_pre[off] = o;
    }
}

// ---------------- RMSNorm + SiLU gate (in place on y_pre) ----------------
__global__ __launch_bounds__(256) void norm_gate(const u16* __restrict__ proj,
                                                 const float* __restrict__ norm_w,
                                                 u16* __restrict__ y) {
    long tok = blockIdx.x;
    int tid = threadIdx.x;
    int c0 = tid * 4;
    u16x4 yv = *(const u16x4*)&y[tok * 1024 + c0];
    float v0 = b2f(yv.x), v1 = b2f(yv.y), v2 = b2f(yv.z), v3 = b2f(yv.w);
    float ss = v0 * v0 + v1 * v1 + v2 * v2 + v3 * v3;
    int lane = tid & 63, w = tid >> 6;
#pragma unroll
    for (int d = 32; d > 0; d >>= 1) ss += __shfl_down(ss, d, 64);
    __shared__ float red[4];
    if (lane == 0) red[w] = ss;
    __syncthreads();
    float tot = red[0] + red[1] + red[2] + red[3];
    float inv = rsqrtf(tot * (1.f / 1024.f) + 1e-6f);
    float4 nw = *(const float4*)&norm_w[c0];
    u16x4 zv = *(const u16x4*)&proj[tok * PROJ_PAD + 1024 + c0];
    float z0 = b2f(zv.x), z1 = b2f(zv.y), z2 = b2f(zv.z), z3 = b2f(zv.w);
    u16x4 o;
    o.x = f2b(v0 * inv * nw.x * (z0 / (1.f + __expf(-z0))));
    o.y = f2b(v1 * inv * nw.y * (z1 / (1.f + __expf(-z1))));
    o.z = f2b(v2 * inv * nw.z * (z2 / (1.f + __expf(-z2))));
    o.w = f2b(v3 * inv * nw.w * (z3 / (1.f + __expf(-z3))));
    *(u16x4*)&y[tok * 1024 + c0] = o;
}

extern "C" void kernel_launch(void* const* d_in, const int* in_sizes, int n_in,
                              void* d_out, int out_size, void* d_ws, size_t ws_size,
                              hipStream_t stream) {
    const float* x      = (const float*)d_in[0];
    const float* W_in   = (const float*)d_in[1];
    const float* dt_W   = (const float*)d_in[2];
    const float* dt_b   = (const float*)d_in[3];
    const float* A_log  = (const float*)d_in[4];
    const float* D_par  = (const float*)d_in[5];
    const float* W_out  = (const float*)d_in[6];
    const float* norm_w = (const float*)d_in[7];
    float* out = (float*)d_out;

    char* ws = (char*)d_ws;
    size_t off = 0;
    auto alloc = [&](size_t b) { void* p = ws + off; off += (b + 255) & ~(size_t)255; return p; };
    u16*   x_bf    = (u16*)alloc((size_t)BTOK * DK * 2);
    u16*   win_bf  = (u16*)alloc((size_t)PROJ_PAD * DK * 2);
    u16*   wout_bf = (u16*)alloc((size_t)DK * DK * 2);
    u16*   proj    = (u16*)alloc((size_t)BTOK * PROJ_PAD * 2);
    float* dt      = (float*)alloc((size_t)BTOK * NH * 4);
    float* dAcs    = (float*)alloc((size_t)BTOK * NH * 4);
    float* decay   = (float*)alloc((size_t)NCH * NH * 4);
    float* cstate  = (float*)alloc((size_t)NCH * NH * NS * HD * 4);
    float* hstates = (float*)alloc((size_t)NCH * NH * NS * HD * 4);
    u16*   y_pre   = (u16*)alloc((size_t)BTOK * DK * 2);
    u16*   y_acc   = x_bf;  // alias: x_bf dead after GEMM1 (stream-ordered)

    cast_bf16<<<BTOK * DK / 4 / 256, 256, 0, stream>>>(x, x_bf, BTOK * DK / 4);
    cast_bf16<<<DK * DK / 4 / 256, 256, 0, stream>>>(W_out, wout_bf, DK * DK / 4);
    cast_pad_win<<<PROJ_PAD * DK / 4 / 256, 256, 0, stream>>>(W_in, win_bf);

    gemm_bt<1><<<dim3(128, 21), 256, 0, stream>>>(x_bf, win_bf, nullptr, proj, DK, PROJ_PAD);

    compute_dt<<<NCH, 64, 0, stream>>>(proj, dt_W, dt_b, A_log, dt, dAcs, decay);
    ssm_intra<<<NCH * NH, 256, 0, stream>>>(proj, dt, dAcs, y_acc, cstate);
    scan_chunks<<<256, 256, 0, stream>>>(cstate, decay, hstates);
    ssm_cross<<<NCH * NH, 256, 0, stream>>>(proj, dAcs, hstates, y_acc, D_par, y_pre);
    norm_gate<<<BTOK, 256, 0, stream>>>(proj, norm_w, y_pre);

    gemm_bt<0><<<dim3(128, 8), 256, 0, stream>>>(y_pre, wout_bf, out, nullptr, DK, DK);
}

// Round 4
// 397.857 us; speedup vs baseline: 1.1989x; 1.0368x over previous
//
#include <hip/hip_runtime.h>

typedef unsigned short u16;
typedef __attribute__((ext_vector_type(8))) short short8;   // 8 bf16 (4 VGPRs) MFMA frag
typedef __attribute__((ext_vector_type(4))) float f32x4;
typedef __attribute__((ext_vector_type(4))) unsigned short u16x4;
typedef __attribute__((ext_vector_type(8))) unsigned short u16x8;

#define BTOK 16384      // B*S = 4*4096
#define PROJ_N 2576
#define PROJ_PAD 2688   // 21 * 128
#define DK 1024         // D_MODEL = D_INNER
#define NCH 256         // B * nChunks = 4*64
#define NH 16
#define HD 64
#define NS 16           // D_STATE

__device__ __forceinline__ float b2f(u16 b) {
    union { unsigned int u; float f; } v; v.u = ((unsigned int)b) << 16; return v.f;
}
__device__ __forceinline__ u16 f2b(float f) {
    union { float f; unsigned int u; } v; v.f = f;
    unsigned int r = v.u + 0x7fffu + ((v.u >> 16) & 1u);
    return (u16)(r >> 16);
}
// async global->LDS, 16B/lane; LDS dest is wave-uniform base + lane*16 (global addr is per-lane)
__device__ __forceinline__ void gl_lds16(const u16* g, u16* l) {
    __builtin_amdgcn_global_load_lds((__attribute__((address_space(1))) void*)g,
                                     (__attribute__((address_space(3))) void*)l,
                                     16, 0, 0);
}

// ---------------- casts ----------------
__global__ __launch_bounds__(256) void cast_bf16(const float* __restrict__ s,
                                                 u16* __restrict__ d, int n4) {
    int t = blockIdx.x * 256 + threadIdx.x;
    if (t < n4) {
        float4 v = ((const float4*)s)[t];
        u16x4 o; o.x = f2b(v.x); o.y = f2b(v.y); o.z = f2b(v.z); o.w = f2b(v.w);
        ((u16x4*)d)[t] = o;
    }
}

__global__ __launch_bounds__(256) void cast_pad_win(const float* __restrict__ s,
                                                    u16* __restrict__ d) {
    int t = blockIdx.x * 256 + threadIdx.x;
    int i4 = t * 4;
    float4 v = make_float4(0.f, 0.f, 0.f, 0.f);
    if (i4 < PROJ_N * DK) v = ((const float4*)s)[t];
    u16x4 o; o.x = f2b(v.x); o.y = f2b(v.y); o.z = f2b(v.z); o.w = f2b(v.w);
    ((u16x4*)d)[t] = o;
}

// ---------------- GEMM: C[M,N] = A[M,K] * B[N,K]^T, bf16 in, fp32 acc ----------------
// global_load_lds width=16 + XOR-swizzled LDS (R3: 0 bank conflicts, ~800 TF)
template <int OUT_BF16>
__global__ __launch_bounds__(256) void gemm_bt(const u16* __restrict__ A,
                                               const u16* __restrict__ B,
                                               float* __restrict__ Cf,
                                               u16* __restrict__ Cb,
                                               int K, int ldc) {
    __shared__ u16 As[128 * 64];
    __shared__ u16 Bs[128 * 64];
    const int tid = threadIdx.x;
    const int bm = blockIdx.x, bn = blockIdx.y;
    const int wave = tid >> 6, lane = tid & 63;
    const int wm = (wave >> 1) * 64, wn = (wave & 1) * 64;
    const int m_l = lane & 15, quad = lane >> 4;

    f32x4 acc[4][4];
#pragma unroll
    for (int i = 0; i < 4; ++i)
#pragma unroll
        for (int j = 0; j < 4; ++j) acc[i][j] = (f32x4){0.f, 0.f, 0.f, 0.f};

    const u16* Ab = A + (long)bm * 128 * K;
    const u16* Bb = B + (long)bn * 128 * K;

    for (int k0 = 0; k0 < K; k0 += 64) {
#pragma unroll
        for (int it = 0; it < 4; ++it) {
            int li = it * 256 + tid;
            int r = li >> 3;
            int k8 = (li & 7) ^ (r & 7);
            u16* lbase = &As[(it * 256 + wave * 64) * 8];   // wave-uniform
            gl_lds16(Ab + (long)r * K + k0 + k8 * 8, lbase);
            u16* lbaseB = &Bs[(it * 256 + wave * 64) * 8];
            gl_lds16(Bb + (long)r * K + k0 + k8 * 8, lbaseB);
        }
        __syncthreads();
#pragma unroll
        for (int ks = 0; ks < 2; ++ks) {
            const int k8 = ks * 4 + quad;
            const int slot = k8 ^ (m_l & 7);     // row&7 == m_l&7 (tile rows are 16-aligned)
            short8 af[4], bf[4];
#pragma unroll
            for (int i = 0; i < 4; ++i) af[i] = *(const short8*)(&As[(wm + i * 16 + m_l) * 64 + slot * 8]);
#pragma unroll
            for (int j = 0; j < 4; ++j) bf[j] = *(const short8*)(&Bs[(wn + j * 16 + m_l) * 64 + slot * 8]);
#pragma unroll
            for (int i = 0; i < 4; ++i)
#pragma unroll
                for (int j = 0; j < 4; ++j)
                    acc[i][j] = __builtin_amdgcn_mfma_f32_16x16x32_bf16(af[i], bf[j], acc[i][j], 0, 0, 0);
        }
        __syncthreads();
    }
    // C/D layout: col=lane&15, row=quad*4+reg (m89/m91 verified)
#pragma unroll
    for (int i = 0; i < 4; ++i) {
        int row_base = bm * 128 + wm + i * 16 + quad * 4;
#pragma unroll
        for (int j = 0; j < 4; ++j) {
            int col = bn * 128 + wn + j * 16 + m_l;
#pragma unroll
            for (int r = 0; r < 4; ++r) {
                float v = acc[i][j][r];
                long off = (long)(row_base + r) * ldc + col;
                if (OUT_BF16) Cb[off] = f2b(v);
                else          Cf[off] = v;
            }
        }
    }
}

// ---------------- intra-chunk: dt fold + scores + y_intra/cstate via MFMA ----------------
// LDS row strides padded (u16: 72, fp32: 20) to break the 128B bank-wrap ->
// fragment ds_read_b128 spreads 8 lanes per 4-bank group (even = 0 counted conflicts).
__global__ __launch_bounds__(256) void ssm_intra(const u16* __restrict__ proj,
                                                 const float* __restrict__ dt_W,
                                                 const float* __restrict__ dt_b,
                                                 const float* __restrict__ A_log,
                                                 float* __restrict__ dAcs,
                                                 float* __restrict__ decay,
                                                 u16* __restrict__ y_acc,
                                                 float* __restrict__ cstate) {
    int bch = blockIdx.x;             // (b*64+c)*16 + h
    int bc = bch >> 4, h = bch & 15;
    long tok0 = (long)bc * 64;
    __shared__ float Cs[64][20], Bm[64][20];
    __shared__ u16 Sh[64][72], Sl[64][72];   // scores hi/lo, [i][j] (A-operand layout)
    __shared__ u16 Xt[64][72];               // X^T: [p][j]   (B-operand for y_intra)
    __shared__ u16 Wh[64][72], Wl[64][72];   // (w*X)^T hi/lo: [p][k] (B-operand for cstate)
    __shared__ u16 Bt[16][72];               // B^T: [n][k]   (A-operand for cstate)
    __shared__ float dts[64], dAs[64], wk[64];
    const int tid = threadIdx.x;
    const int wave = tid >> 6, lane = tid & 63;
    const int m_l = lane & 15, quad = lane >> 4;

    // wave 0: dt = softplus(dt_low @ dt_W^T + dt_b), dA cumsum, decay (lane = token)
    if (tid < 64) {
        long tok = tok0 + tid;
        u16x8 lo0 = *(const u16x8*)&proj[tok * PROJ_PAD + 2560];
        u16x8 lo1 = *(const u16x8*)&proj[tok * PROJ_PAD + 2568];
        float a = dt_b[h];
#pragma unroll
        for (int r = 0; r < 8; ++r) a += b2f(lo0[r]) * dt_W[h * 16 + r];
#pragma unroll
        for (int r = 0; r < 8; ++r) a += b2f(lo1[r]) * dt_W[h * 16 + 8 + r];
        float d = (a > 20.f) ? a : log1pf(__expf(a));
        float dA = -__expf(A_log[h]) * d;
        float cs = dA;
#pragma unroll
        for (int off = 1; off < 64; off <<= 1) {
            float o = __shfl_up(cs, off, 64);
            if (tid >= off) cs += o;
        }
        float cs63 = __shfl(cs, 63, 64);
        dts[tid] = d;
        dAs[tid] = cs;
        wk[tid] = d * __expf(cs63 - cs);
        dAcs[tok * 16 + h] = cs;
        if (tid == 63) decay[bc * 16 + h] = __expf(cs);
    }
#pragma unroll
    for (int it = 0; it < 4; ++it) {
        int li = it * 256 + tid;
        int i = li >> 4, n = li & 15;
        u16 cb = proj[(tok0 + i) * PROJ_PAD + 2304 + h * 16 + n];
        u16 bb = proj[(tok0 + i) * PROJ_PAD + 2048 + h * 16 + n];
        Cs[i][n] = b2f(cb);
        Bm[i][n] = b2f(bb);
        Bt[n][i] = bb;
    }
    __syncthreads();   // dt/wk + C/B ready
    // X load: transpose + w-scale (hi/lo split keeps full fp32 precision through MFMA)
#pragma unroll
    for (int it = 0; it < 2; ++it) {
        int li = it * 256 + tid;
        int j = li & 63, p0 = (li >> 6) * 8;
        u16x8 xv = *(const u16x8*)&proj[(tok0 + j) * PROJ_PAD + h * 64 + p0];
        float w = wk[j];
#pragma unroll
        for (int t = 0; t < 8; ++t) {
            u16 xb = xv[t];
            Xt[p0 + t][j] = xb;
            float v = w * b2f(xb);
            u16 hi = f2b(v);
            Wh[p0 + t][j] = hi;
            Wl[p0 + t][j] = f2b(v - b2f(hi));
        }
    }
    // scores (fp32 VALU): S[i][j] = (C_i . B_j) * exp(dA_i - dA_j) * dt_j, causal
    {
        int j = tid & 63, i0 = tid >> 6;
#pragma unroll
        for (int g = 0; g < 16; ++g) {
            int i = i0 + g * 4;
            float v = 0.f;
            if (j <= i) {
                float d = 0.f;
                const f32x4* cp = (const f32x4*)Cs[i];
                const f32x4* bp = (const f32x4*)Bm[j];
#pragma unroll
                for (int n4 = 0; n4 < 4; ++n4) {
                    f32x4 c = cp[n4], b = bp[n4];
                    d += c.x * b.x + c.y * b.y + c.z * b.z + c.w * b.w;
                }
                v = d * __expf(dAs[i] - dAs[j]) * dts[j];
            }
            u16 hi = f2b(v);
            Sh[i][j] = hi;
            Sl[i][j] = f2b(v - b2f(hi));
        }
    }
    __syncthreads();
    // y_intra: wave w owns i-tile w (16 rows), 4 p-tiles, K=64 over j, hi+lo
    {
        f32x4 yv[4];
#pragma unroll
        for (int jt = 0; jt < 4; ++jt) yv[jt] = (f32x4){0.f, 0.f, 0.f, 0.f};
#pragma unroll
        for (int ks = 0; ks < 2; ++ks) {
            int kc = ks * 32 + quad * 8;
            short8 ah = *(const short8*)&Sh[wave * 16 + m_l][kc];
            short8 al = *(const short8*)&Sl[wave * 16 + m_l][kc];
#pragma unroll
            for (int jt = 0; jt < 4; ++jt) {
                short8 bx = *(const short8*)&Xt[jt * 16 + m_l][kc];
                yv[jt] = __builtin_amdgcn_mfma_f32_16x16x32_bf16(ah, bx, yv[jt], 0, 0, 0);
                yv[jt] = __builtin_amdgcn_mfma_f32_16x16x32_bf16(al, bx, yv[jt], 0, 0, 0);
            }
        }
#pragma unroll
        for (int jt = 0; jt < 4; ++jt)
#pragma unroll
            for (int r = 0; r < 4; ++r) {
                int i = wave * 16 + quad * 4 + r;
                int p = jt * 16 + m_l;
                y_acc[(tok0 + i) * 1024 + h * 64 + p] = f2b(yv[jt][r]);
            }
    }
    // cstate: wave w owns p-tile w; out [n=16][p=16], K=64 over tokens, hi+lo
    {
        f32x4 cacc = (f32x4){0.f, 0.f, 0.f, 0.f};
#pragma unroll
        for (int ks = 0; ks < 2; ++ks) {
            int kc = ks * 32 + quad * 8;
            short8 a = *(const short8*)&Bt[m_l][kc];
            short8 bh = *(const short8*)&Wh[wave * 16 + m_l][kc];
            short8 bl = *(const short8*)&Wl[wave * 16 + m_l][kc];
            cacc = __builtin_amdgcn_mfma_f32_16x16x32_bf16(a, bh, cacc, 0, 0, 0);
            cacc = __builtin_amdgcn_mfma_f32_16x16x32_bf16(a, bl, cacc, 0, 0, 0);
        }
#pragma unroll
        for (int r = 0; r < 4; ++r) {
            int n = quad * 4 + r;
            int p = wave * 16 + m_l;
            cstate[(long)bch * 1024 + n * 64 + p] = cacc[r];
        }
    }
}

// ---------------- sequential scan over chunks ----------------
__global__ __launch_bounds__(256) void scan_chunks(const float* __restrict__ cs,
                                                   const float* __restrict__ decay,
                                                   float* __restrict__ hs) {
    int t = blockIdx.x * 256 + threadIdx.x;
    int p = t & 63, n = (t >> 6) & 15, h = (t >> 10) & 15, b = t >> 14;
    float state = 0.f;
    for (int c = 0; c < 64; ++c) {
        long idx = (((long)((b * 64 + c) * 16 + h)) * 16 + n) * 64 + p;
        hs[idx] = state;
        state = decay[(b * 64 + c) * 16 + h] * state + cs[idx];
    }
}

// ---------------- y_cross + skip ----------------
__global__ __launch_bounds__(256) void ssm_cross(const u16* __restrict__ proj,
                                                 const float* __restrict__ dAcs,
                                                 const float* __restrict__ hs,
                                                 const u16* __restrict__ y_acc,
                                                 const float* __restrict__ D_param,
                                                 u16* __restrict__ y_pre) {
    int bch = blockIdx.x;
    int bc = bch >> 4, h = bch & 15;
    long tok0 = (long)bc * 64;
    __shared__ float hss[16][64], Cs[64][16], dAs[64];
    int tid = threadIdx.x;
#pragma unroll
    for (int it = 0; it < 4; ++it) {
        int li = it * 256 + tid;
        hss[li >> 6][li & 63] = hs[(long)bch * 1024 + li];
        int i = li >> 4, n = li & 15;
        Cs[i][n] = b2f(proj[(tok0 + i) * PROJ_PAD + 2304 + h * 16 + n]);
    }
    if (tid < 64) dAs[tid] = dAcs[(tok0 + tid) * 16 + h];
    __syncthreads();
    float Dh = D_param[h];
    int pi = (tid & 15) * 4;
    int ib = tid >> 4;
#pragma unroll
    for (int g = 0; g < 4; ++g) {
        int i = ib + 16 * g;
        f32x4 cr = (f32x4){0.f, 0.f, 0.f, 0.f};
#pragma unroll
        for (int n = 0; n < 16; ++n) {
            float c = Cs[i][n];
            cr += c * *(const f32x4*)&hss[n][pi];
        }
        float e = __expf(dAs[i]);
        long off = (tok0 + i) * 1024 + h * 64 + pi;
        u16x4 ya = *(const u16x4*)&y_acc[off];
        u16x4 xv = *(const u16x4*)&proj[(tok0 + i) * PROJ_PAD + h * 64 + pi];
        u16x4 o;
        o.x = f2b(b2f(ya.x) + e * cr.x + b2f(xv.x) * Dh);
        o.y = f2b(b2f(ya.y) + e * cr.y + b2f(xv.y) * Dh);
        o.z = f2b(b2f(ya.z) + e * cr.z + b2f(xv.z) * Dh);
        o.w = f2b(b2f(ya.w) + e * cr.w + b2f(xv.w) * Dh);
        *(u16x4*)&y_pre[off] = o;
    }
}

// ---------------- RMSNorm + SiLU gate (in place on y_pre) ----------------
__global__ __launch_bounds__(256) void norm_gate(const u16* __restrict__ proj,
                                                 const float* __restrict__ norm_w,
                                                 u16* __restrict__ y) {
    long tok = blockIdx.x;
    int tid = threadIdx.x;
    int c0 = tid * 4;
    u16x4 yv = *(const u16x4*)&y[tok * 1024 + c0];
    float v0 = b2f(yv.x), v1 = b2f(yv.y), v2 = b2f(yv.z), v3 = b2f(yv.w);
    float ss = v0 * v0 + v1 * v1 + v2 * v2 + v3 * v3;
    int lane = tid & 63, w = tid >> 6;
#pragma unroll
    for (int d = 32; d > 0; d >>= 1) ss += __shfl_down(ss, d, 64);
    __shared__ float red[4];
    if (lane == 0) red[w] = ss;
    __syncthreads();
    float tot = red[0] + red[1] + red[2] + red[3];
    float inv = rsqrtf(tot * (1.f / 1024.f) + 1e-6f);
    float4 nw = *(const float4*)&norm_w[c0];
    u16x4 zv = *(const u16x4*)&proj[tok * PROJ_PAD + 1024 + c0];
    float z0 = b2f(zv.x), z1 = b2f(zv.y), z2 = b2f(zv.z), z3 = b2f(zv.w);
    u16x4 o;
    o.x = f2b(v0 * inv * nw.x * (z0 / (1.f + __expf(-z0))));
    o.y = f2b(v1 * inv * nw.y * (z1 / (1.f + __expf(-z1))));
    o.z = f2b(v2 * inv * nw.z * (z2 / (1.f + __expf(-z2))));
    o.w = f2b(v3 * inv * nw.w * (z3 / (1.f + __expf(-z3))));
    *(u16x4*)&y[tok * 1024 + c0] = o;
}

extern "C" void kernel_launch(void* const* d_in, const int* in_sizes, int n_in,
                              void* d_out, int out_size, void* d_ws, size_t ws_size,
                              hipStream_t stream) {
    const float* x      = (const float*)d_in[0];
    const float* W_in   = (const float*)d_in[1];
    const float* dt_W   = (const float*)d_in[2];
    const float* dt_b   = (const float*)d_in[3];
    const float* A_log  = (const float*)d_in[4];
    const float* D_par  = (const float*)d_in[5];
    const float* W_out  = (const float*)d_in[6];
    const float* norm_w = (const float*)d_in[7];
    float* out = (float*)d_out;

    char* ws = (char*)d_ws;
    size_t off = 0;
    auto alloc = [&](size_t b) { void* p = ws + off; off += (b + 255) & ~(size_t)255; return p; };
    u16*   x_bf    = (u16*)alloc((size_t)BTOK * DK * 2);
    u16*   win_bf  = (u16*)alloc((size_t)PROJ_PAD * DK * 2);
    u16*   wout_bf = (u16*)alloc((size_t)DK * DK * 2);
    u16*   proj    = (u16*)alloc((size_t)BTOK * PROJ_PAD * 2);
    float* dAcs    = (float*)alloc((size_t)BTOK * NH * 4);
    float* decay   = (float*)alloc((size_t)NCH * NH * 4);
    float* cstate  = (float*)alloc((size_t)NCH * NH * NS * HD * 4);
    float* hstates = (float*)alloc((size_t)NCH * NH * NS * HD * 4);
    u16*   y_pre   = (u16*)alloc((size_t)BTOK * DK * 2);
    u16*   y_acc   = x_bf;  // alias: x_bf dead after GEMM1 (stream-ordered)

    cast_bf16<<<BTOK * DK / 4 / 256, 256, 0, stream>>>(x, x_bf, BTOK * DK / 4);
    cast_bf16<<<DK * DK / 4 / 256, 256, 0, stream>>>(W_out, wout_bf, DK * DK / 4);
    cast_pad_win<<<PROJ_PAD * DK / 4 / 256, 256, 0, stream>>>(W_in, win_bf);

    gemm_bt<1><<<dim3(128, 21), 256, 0, stream>>>(x_bf, win_bf, nullptr, proj, DK, PROJ_PAD);

    ssm_intra<<<NCH * NH, 256, 0, stream>>>(proj, dt_W, dt_b, A_log, dAcs, decay, y_acc, cstate);
    scan_chunks<<<256, 256, 0, stream>>>(cstate, decay, hstates);
    ssm_cross<<<NCH * NH, 256, 0, stream>>>(proj, dAcs, hstates, y_acc, D_par, y_pre);
    norm_gate<<<BTOK, 256, 0, stream>>>(proj, norm_w, y_pre);

    gemm_bt<0><<<dim3(128, 8), 256, 0, stream>>>(y_pre, wout_bf, out, nullptr, DK, DK);
}